// Round 3
// baseline (340.823 us; speedup 1.0000x reference)
//
#include <hip/hip_runtime.h>
#include <hip/hip_bf16.h>
#include <stdint.h>

#define N_PTS   100000
#define D       512
#define KDIM    256
#define NWORDS  1564         // sign words per column: 100096/64
#define NW      1563         // crossing words (ceil(99999/64))
#define GRIDX   3128         // 4 * 782 blocks
#define CHUNK   391          // 3128 / 8 XCDs

typedef float  f32x4  __attribute__((ext_vector_type(4)));
typedef __bf16 bf16x8 __attribute__((ext_vector_type(8)));

// ---------- K0: build W bf16 [512 rows j][512 cols d] ----------
__global__ void build_w(const float* __restrict__ theta,
                        const float* __restrict__ noise,
                        __bf16* __restrict__ W) {
    int idx = blockIdx.x * 256 + threadIdx.x;   // 0..262143
    int j = idx >> 9;
    int d = idx & 511;
    float v;
    if (j < KDIM) v = theta[j * D + d];
    else          v = theta[(j - KDIM) * D + d] + 0.01f * noise[(j - KDIM) * D + d];
    W[idx] = (__bf16)v;
}

// ---------- K1: barrier-free direct-fragment MFMA GEMM -> packed sign bits ----------
// No LDS in the main loop: A fragments (8 consecutive f32 of one basis row)
// and B fragments (8 consecutive bf16 of one W row) are loaded straight from
// global, register double-buffered at distance 1. f32->bf16 cvt in-reg.
// LDS used only for the epilogue sign transpose/pack.
__global__ void __launch_bounds__(256, 2)
gemm_signs(const float* __restrict__ basis,
           const __bf16* __restrict__ W,
           uint64_t* __restrict__ sbits) {
    __shared__ unsigned char sb[128 * 132];   // epilogue only (pad kills conflicts)

    const int tid  = threadIdx.x;
    const int lane = tid & 63;
    const int wave = tid >> 6;
    const int wrow = wave >> 1;     // 0..1
    const int wcol = wave & 1;      // 0..1

    // XCD-chunk swizzle: the 4 bn-blocks sharing an A-panel land on one XCD L2.
    const int phys = blockIdx.x;
    const int lid  = (phys & 7) * CHUNK + (phys >> 3);
    const int bn   = lid & 3;       // 0..3   column tile
    const int bm   = lid >> 2;      // 0..781 row tile

    const int lane16 = lane & 15;
    const int lgrp   = lane >> 4;

    // per-lane fragment base pointers (kt advances by imm offsets, 128B/64B)
    const float*  ap[4];
    const __bf16* bp[4];
    #pragma unroll
    for (int m = 0; m < 4; ++m) {
        int r = bm * 128 + wrow * 64 + m * 16 + lane16;
        if (r > N_PTS - 1) r = N_PTS - 1;              // tail clamp (bits masked in K2)
        ap[m] = basis + (size_t)r * D + lgrp * 8;
    }
    #pragma unroll
    for (int n = 0; n < 4; ++n) {
        int c = bn * 128 + wcol * 64 + n * 16 + lane16;
        bp[n] = W + (size_t)c * D + lgrp * 8;
    }

    f32x4  acc[4][4] = {};
    float4 ra[2][4][2];
    uint4  rb[2][4];

    // prologue: prefetch kt=0
    #pragma unroll
    for (int m = 0; m < 4; ++m) {
        ra[0][m][0] = *(const float4*)(ap[m]);
        ra[0][m][1] = *(const float4*)(ap[m] + 4);
    }
    #pragma unroll
    for (int n = 0; n < 4; ++n) rb[0][n] = *(const uint4*)(bp[n]);

    #pragma unroll
    for (int kt = 0; kt < 16; ++kt) {
        const int cur = kt & 1, nxt = cur ^ 1;

        // issue next K-step loads; they stay in flight under this step's MFMAs
        if (kt < 15) {
            #pragma unroll
            for (int m = 0; m < 4; ++m) {
                ra[nxt][m][0] = *(const float4*)(ap[m] + (kt + 1) * 32);
                ra[nxt][m][1] = *(const float4*)(ap[m] + (kt + 1) * 32 + 4);
            }
            #pragma unroll
            for (int n = 0; n < 4; ++n)
                rb[nxt][n] = *(const uint4*)(bp[n] + (kt + 1) * 32);
        }

        // in-reg f32 -> bf16 for A (compiler inserts the right vmcnt wait)
        bf16x8 af[4], bfm[4];
        #pragma unroll
        for (int m = 0; m < 4; ++m) {
            af[m][0] = (__bf16)ra[cur][m][0].x;
            af[m][1] = (__bf16)ra[cur][m][0].y;
            af[m][2] = (__bf16)ra[cur][m][0].z;
            af[m][3] = (__bf16)ra[cur][m][0].w;
            af[m][4] = (__bf16)ra[cur][m][1].x;
            af[m][5] = (__bf16)ra[cur][m][1].y;
            af[m][6] = (__bf16)ra[cur][m][1].z;
            af[m][7] = (__bf16)ra[cur][m][1].w;
        }
        #pragma unroll
        for (int n = 0; n < 4; ++n) bfm[n] = *(bf16x8*)&rb[cur][n];

        #pragma unroll
        for (int m = 0; m < 4; ++m)
            #pragma unroll
            for (int n = 0; n < 4; ++n)
                acc[m][n] = __builtin_amdgcn_mfma_f32_16x16x32_bf16(af[m], bfm[n], acc[m][n], 0, 0, 0);
    }

    // ---- epilogue: sign bytes -> LDS transpose -> multiply-pack -> u64 words ----
    // C/D layout: col = lane&15, row = (lane>>4)*4 + reg
    #pragma unroll
    for (int m = 0; m < 4; ++m) {
        #pragma unroll
        for (int n = 0; n < 4; ++n) {
            const int cl = wcol * 64 + n * 16 + lane16;            // local col 0..127
            const int rw = wrow * 64 + m * 16 + lgrp * 4;          // local row base
            uint32_t pk = 0;
            #pragma unroll
            for (int r = 0; r < 4; ++r)
                pk |= (acc[m][n][r] < 0.0f ? 1u : 0u) << (8 * r);
            *(uint32_t*)&sb[cl * 132 + rw] = pk;                   // 4 rows as one u32
        }
    }
    __syncthreads();

    // pack: thread -> (col 0..127, half 0..1); 64 sign bytes -> u64
    {
        const int col  = tid >> 1;
        const int half = tid & 1;
        const unsigned char* src = &sb[col * 132 + half * 64];
        uint64_t wbits = 0;
        #pragma unroll
        for (int k = 0; k < 16; ++k) {
            uint32_t q  = *(const uint32_t*)&src[4 * k];
            uint32_t p4 = ((q & 0x01010101u) * 0x10204080u) >> 28;  // 4 bytes -> 4 bits
            wbits |= (uint64_t)p4 << (4 * k);
        }
        sbits[(size_t)(bm * 2 + half) * 512 + bn * 128 + col] = wbits;  // coalesced
    }
}

// ---------- K2: crossing masks from sign bits ----------
// maskT[w][j] bit b = (s[n]^s[n+1])_raw & (s[n]^s[n+1])_pert, n = 64w+b
__global__ void crossing_masks(const uint64_t* __restrict__ sbits,
                               uint64_t* __restrict__ maskT) {
    const int w = blockIdx.x;       // 0..1562
    const int j = threadIdx.x;      // 0..255
    uint64_t s0r = sbits[(size_t)w * 512 + j];
    uint64_t s0p = sbits[(size_t)w * 512 + 256 + j];
    uint64_t s1r = sbits[(size_t)(w + 1) * 512 + j];
    uint64_t s1p = sbits[(size_t)(w + 1) * 512 + 256 + j];
    uint64_t cr = s0r ^ ((s0r >> 1) | (s1r << 63));
    uint64_t cp = s0p ^ ((s0p >> 1) | (s1p << 63));
    uint64_t m = cr & cp;
    if (w == NW - 1) m &= 0x7FFFFFFFull;    // 31 valid crossings in last word
    maskT[(size_t)w * 256 + j] = m;
}

// ---------- K3: pairwise AND-popcount ----------
__global__ void zero_out(float* __restrict__ out) {
    int i = blockIdx.x * 256 + threadIdx.x;
    if (i < 32640) out[i] = 0.0f;
}

__global__ void pair_popcount(const uint64_t* __restrict__ maskT,
                              float* __restrict__ out) {
    const int i = blockIdx.x;   // 0..255
    const int c = blockIdx.y;   // 0..3 word chunk
    const int j = threadIdx.x;  // 0..255
    if (j <= i) return;
    int w0 = c * 391;
    int w1 = w0 + 391; if (w1 > NW) w1 = NW;
    uint32_t sum = 0;
    #pragma unroll 4
    for (int w = w0; w < w1; ++w) {
        uint64_t mi = maskT[(size_t)w * 256 + i];   // block-uniform -> scalar
        uint64_t mj = maskT[(size_t)w * 256 + j];   // coalesced
        sum += (uint32_t)__popcll(mi & mj);
    }
    const size_t idx = (size_t)i * (2 * KDIM - i - 1) / 2 + (size_t)(j - i - 1);
    atomicAdd(&out[idx], (float)sum);   // exact-integer f32 adds -> deterministic
}

extern "C" void kernel_launch(void* const* d_in, const int* in_sizes, int n_in,
                              void* d_out, int out_size, void* d_ws, size_t ws_size,
                              hipStream_t stream) {
    const float* theta = (const float*)d_in[0];   // [256,512]
    const float* basis = (const float*)d_in[1];   // [100000,512]
    const float* noise = (const float*)d_in[2];   // [256,512]
    float* out = (float*)d_out;                   // [32640]

    char* ws = (char*)d_ws;
    __bf16*   W     = (__bf16*)ws;                              // 512 KB
    uint64_t* sbits = (uint64_t*)(ws + 524288);                 // 1564*512*8 = 6.41 MB
    uint64_t* maskT = (uint64_t*)(ws + 524288 + (size_t)NWORDS * 512 * 8); // 3.2 MB

    hipLaunchKernelGGL(build_w,        dim3(1024),    dim3(256), 0, stream, theta, noise, W);
    hipLaunchKernelGGL(gemm_signs,     dim3(GRIDX),   dim3(256), 0, stream, basis, W, sbits);
    hipLaunchKernelGGL(crossing_masks, dim3(NW),      dim3(256), 0, stream, sbits, maskT);
    hipLaunchKernelGGL(zero_out,       dim3(128),     dim3(256), 0, stream, out);
    hipLaunchKernelGGL(pair_popcount,  dim3(KDIM, 4), dim3(256), 0, stream, maskT, out);
}

// Round 4
// 125.369 us; speedup vs baseline: 2.7186x; 2.7186x over previous
//
#include <hip/hip_runtime.h>
#include <hip/hip_bf16.h>
#include <stdint.h>

#define KDIM    256
#define NWORDS  1564         // sign words per column: 782 blocks * 2
#define NW      1563         // crossing words (ceil(99999/64))
#define GEMM_GRID 1564       // 782 bm * 2 bn

typedef float  f32x4  __attribute__((ext_vector_type(4)));
typedef __bf16 bf16x8 __attribute__((ext_vector_type(8)));

__device__ __forceinline__ void gl_lds16(const void* g, void* l) {
    __builtin_amdgcn_global_load_lds(
        (const __attribute__((address_space(1))) unsigned int*)g,
        (__attribute__((address_space(3))) unsigned int*)l, 16, 0, 0);
}

// ---------- K0: build W bf16 [512 rows j][512 cols d] ----------
__global__ void build_w(const float* __restrict__ theta,
                        const float* __restrict__ noise,
                        __bf16* __restrict__ W) {
    int idx = blockIdx.x * 256 + threadIdx.x;   // 0..262143
    int j = idx >> 9;
    int d = idx & 511;
    float v;
    if (j < KDIM) v = theta[j * 512 + d];
    else          v = theta[(j - KDIM) * 512 + d] + 0.01f * noise[(j - KDIM) * 512 + d];
    W[idx] = (__bf16)v;
}

// ---------- K1: DMA-staged MFMA GEMM -> packed sign bits ----------
// BM=128 x BN=256, BK=32, 512 threads (8 waves, 2M x 4N, wave-tile 64x64).
// global_load_lds (16B) stages raw f32 A / bf16 B; XOR granule swizzle applied
// on the GLOBAL source (LDS dest stays linear, rule 21) and on the ds_read.
// Counted vmcnt(4): next tile's 4 DMA loads stay in flight across barriers.
// f32->bf16 cvt on the read side. Epilogue packs signs to u64 words.
__global__ void __launch_bounds__(512, 2)
gemm_signs(const float* __restrict__ basis,
           const __bf16* __restrict__ W,
           uint64_t* __restrict__ sbits) {
    __shared__ char smem[65536];   // A: [2][128r][128B] @0; B: [2][256c][64B] @32768

    const int tid    = threadIdx.x;
    const int lane   = tid & 63;
    const int wave   = tid >> 6;
    const int wr     = wave >> 2;      // 0..1
    const int wc     = wave & 3;       // 0..3
    const int lane16 = lane & 15;
    const int lgrp   = lane >> 4;

    // bijective XCD swizzle: nwg=1564=8*195+4 (m204): adjacent wgid -> same XCD
    const int orig = blockIdx.x;
    const int xcd  = orig & 7;
    const int wgid = (xcd < 4 ? xcd * 196 : 784 + (xcd - 4) * 195) + (orig >> 3);
    const int bn   = wgid & 1;     // 0..1
    const int bm   = wgid >> 1;    // 0..781

    // ---- staging: 4 global_load_lds per wave per K-tile ----
    auto stage = [&](int t) {
        char* abase = smem + ((t & 1) << 14);
        char* bbase = smem + 32768 + ((t & 1) << 14);
        #pragma unroll
        for (int i = 0; i < 2; ++i) {   // A: rows wave*16+i*8 .. +7, 1KB each
            int r = wave * 16 + i * 8 + (lane >> 3);   // local row 0..127
            int g = lane & 7;                          // 16B granule in 128B row
            int rg = bm * 128 + r; if (rg > 99999) rg = 99999;
            const float* src = basis + (size_t)rg * 512 + t * 32 + ((g ^ (r & 7)) << 2);
            gl_lds16(src, abase + (wave * 16 + i * 8) * 128);
        }
        #pragma unroll
        for (int i = 0; i < 2; ++i) {   // B: cols wave*32+i*16 .. +15, 1KB each
            int c = wave * 32 + i * 16 + (lane >> 2);  // local col 0..255
            int g = lane & 3;                          // 16B granule in 64B row
            const __bf16* src = W + (size_t)(bn * 256 + c) * 512 + t * 32
                                  + ((g ^ ((c >> 1) & 3)) << 3);
            gl_lds16(src, bbase + (wave * 32 + i * 16) * 64);
        }
    };

    stage(0);
    stage(1);                      // 8 loads in flight per wave

    f32x4 acc[4][4] = {};
    const int s = lane16 & 7;

    #pragma unroll
    for (int t = 0; t < 16; ++t) {
        // drain tile t's loads (4 of tile t+1 stay in flight), then barrier
        if (t < 15) asm volatile("s_waitcnt vmcnt(4)\ns_barrier" ::: "memory");
        else        asm volatile("s_waitcnt vmcnt(0)\ns_barrier" ::: "memory");

        const char* ab = smem + ((t & 1) << 14);
        const char* bb = smem + 32768 + ((t & 1) << 14);

        // B fragments (held across both phases)
        bf16x8 bf[4];
        #pragma unroll
        for (int n = 0; n < 4; ++n) {
            int cc = wc * 64 + n * 16 + lane16;
            int gb = lgrp ^ ((cc >> 1) & 3);
            bf[n] = *(const bf16x8*)(bb + cc * 64 + gb * 16);
        }

        #pragma unroll
        for (int mh = 0; mh < 2; ++mh) {       // two phases of 2m x 4n MFMAs
            bf16x8 af[2];
            #pragma unroll
            for (int mi = 0; mi < 2; ++mi) {
                int rr = wr * 64 + (mh * 2 + mi) * 16 + lane16;
                f32x4 lo = *(const f32x4*)(ab + rr * 128 + (((2 * lgrp + 0) ^ s) << 4));
                f32x4 hi = *(const f32x4*)(ab + rr * 128 + (((2 * lgrp + 1) ^ s) << 4));
                af[mi][0] = (__bf16)lo[0]; af[mi][1] = (__bf16)lo[1];
                af[mi][2] = (__bf16)lo[2]; af[mi][3] = (__bf16)lo[3];
                af[mi][4] = (__bf16)hi[0]; af[mi][5] = (__bf16)hi[1];
                af[mi][6] = (__bf16)hi[2]; af[mi][7] = (__bf16)hi[3];
            }
            __builtin_amdgcn_s_setprio(1);
            #pragma unroll
            for (int mi = 0; mi < 2; ++mi)
                #pragma unroll
                for (int n = 0; n < 4; ++n)
                    acc[mh * 2 + mi][n] = __builtin_amdgcn_mfma_f32_16x16x32_bf16(
                        af[mi], bf[n], acc[mh * 2 + mi][n], 0, 0, 0);
            __builtin_amdgcn_s_setprio(0);
        }

        asm volatile("s_barrier" ::: "memory");   // all waves done reading tile t
        if (t < 14) stage(t + 2);                 // overwrite freed parity buffer
    }

    // ---- epilogue: sign bytes -> LDS transpose -> multiply-pack -> u64 ----
    // C/D layout: col = lane&15, row = (lane>>4)*4 + reg
    unsigned char* sb = (unsigned char*)smem;     // [256 cols][136B] = 34.8KB
    #pragma unroll
    for (int m = 0; m < 4; ++m) {
        #pragma unroll
        for (int n = 0; n < 4; ++n) {
            int cc = wc * 64 + n * 16 + lane16;          // local col 0..255
            int rb = wr * 64 + m * 16 + lgrp * 4;        // local row base 0..124
            uint32_t pk = 0;
            #pragma unroll
            for (int r = 0; r < 4; ++r)
                pk |= (acc[m][n][r] < 0.0f ? 1u : 0u) << (8 * r);
            *(uint32_t*)&sb[cc * 136 + rb] = pk;
        }
    }
    asm volatile("s_waitcnt lgkmcnt(0)\ns_barrier" ::: "memory");

    {   // thread -> (col 0..255, word-half 0..1); 64 sign bytes -> u64
        const int col = tid & 255;
        const int wh  = tid >> 8;
        const unsigned char* src = &sb[col * 136 + wh * 64];
        uint64_t wbits = 0;
        #pragma unroll
        for (int k = 0; k < 16; ++k) {
            uint32_t q  = *(const uint32_t*)&src[4 * k];
            uint32_t p4 = ((q & 0x01010101u) * 0x10204080u) >> 28;
            wbits |= (uint64_t)p4 << (4 * k);
        }
        sbits[(size_t)(bm * 2 + wh) * 512 + bn * 256 + col] = wbits;  // coalesced
    }
}

// ---------- K2: crossing masks from sign bits ----------
__global__ void crossing_masks(const uint64_t* __restrict__ sbits,
                               uint64_t* __restrict__ maskT) {
    const int w = blockIdx.x;       // 0..1562
    const int j = threadIdx.x;      // 0..255
    uint64_t s0r = sbits[(size_t)w * 512 + j];
    uint64_t s0p = sbits[(size_t)w * 512 + 256 + j];
    uint64_t s1r = sbits[(size_t)(w + 1) * 512 + j];
    uint64_t s1p = sbits[(size_t)(w + 1) * 512 + 256 + j];
    uint64_t cr = s0r ^ ((s0r >> 1) | (s1r << 63));
    uint64_t cp = s0p ^ ((s0p >> 1) | (s1p << 63));
    uint64_t m = cr & cp;
    if (w == NW - 1) m &= 0x7FFFFFFFull;    // 31 valid crossings in last word
    maskT[(size_t)w * 256 + j] = m;
}

// ---------- K3: pairwise AND-popcount ----------
__global__ void zero_out(float* __restrict__ out) {
    int i = blockIdx.x * 256 + threadIdx.x;
    if (i < 32640) out[i] = 0.0f;
}

__global__ void pair_popcount(const uint64_t* __restrict__ maskT,
                              float* __restrict__ out) {
    const int i = blockIdx.x;   // 0..255
    const int c = blockIdx.y;   // 0..3 word chunk
    const int j = threadIdx.x;  // 0..255
    if (j <= i) return;
    int w0 = c * 391;
    int w1 = w0 + 391; if (w1 > NW) w1 = NW;
    uint32_t sum = 0;
    #pragma unroll 4
    for (int w = w0; w < w1; ++w) {
        uint64_t mi = maskT[(size_t)w * 256 + i];   // block-uniform -> scalar
        uint64_t mj = maskT[(size_t)w * 256 + j];   // coalesced
        sum += (uint32_t)__popcll(mi & mj);
    }
    const size_t idx = (size_t)i * (2 * KDIM - i - 1) / 2 + (size_t)(j - i - 1);
    atomicAdd(&out[idx], (float)sum);   // exact-integer f32 adds -> deterministic
}

extern "C" void kernel_launch(void* const* d_in, const int* in_sizes, int n_in,
                              void* d_out, int out_size, void* d_ws, size_t ws_size,
                              hipStream_t stream) {
    const float* theta = (const float*)d_in[0];   // [256,512]
    const float* basis = (const float*)d_in[1];   // [100000,512]
    const float* noise = (const float*)d_in[2];   // [256,512]
    float* out = (float*)d_out;                   // [32640]

    char* ws = (char*)d_ws;
    __bf16*   W     = (__bf16*)ws;                              // 512 KB
    uint64_t* sbits = (uint64_t*)(ws + 524288);                 // 1564*512*8 = 6.41 MB
    uint64_t* maskT = (uint64_t*)(ws + 524288 + (size_t)NWORDS * 512 * 8); // 3.2 MB

    hipLaunchKernelGGL(build_w,        dim3(1024),     dim3(256), 0, stream, theta, noise, W);
    hipLaunchKernelGGL(gemm_signs,     dim3(GEMM_GRID),dim3(512), 0, stream, basis, W, sbits);
    hipLaunchKernelGGL(crossing_masks, dim3(NW),       dim3(256), 0, stream, sbits, maskT);
    hipLaunchKernelGGL(zero_out,       dim3(128),      dim3(256), 0, stream, out);
    hipLaunchKernelGGL(pair_popcount,  dim3(KDIM, 4),  dim3(256), 0, stream, maskT, out);
}